// Round 1
// baseline (894.195 us; speedup 1.0000x reference)
//
#include <hip/hip_runtime.h>
#include <hip/hip_fp16.h>
#include <math.h>

#define UNITS   50
#define K3      150     // 3*UNITS
#define KP      160     // padded gate-column count (mult of 4, >=150)
#define KP2     80      // half2 per weight row
#define FDIM    64
#define TSTEPS  128
#define BATCH   4096
#define NB      8       // batch elements per block
#define KLANES  40      // k-thread groups (4 cols each)
#define NTHREADS 320    // KLANES * NB, 5 waves
#define BP      9       // batch pad (odd -> 2-way max on LDS banks)

// LDS budget (static, must stay < 64 KB):
//   Wh2: 64*80*4  = 20480 B   (W as half2, cols padded w/ zeros)
//   Uh2: 50*80*4  = 16000 B
//   xs : 64*9*4   =  2304 B   (x_t staged, [f][b])
//   hs : 50*9*4   =  1800 B   (h state,   [u][b])
//   sX : 160*9*4  =  5760 B   (xp partials [k][b])
//   sU : 160*9*4  =  5760 B   (hp partials [k][b])
//   total         = 52104 B -> 2-3 blocks/CU (LDS 160K/CU), 10-15 waves/CU

__global__ __launch_bounds__(NTHREADS)
void gru_fused(const float* __restrict__ x, const float* __restrict__ W,
               const float* __restrict__ U, const float* __restrict__ bias,
               const float* __restrict__ Wd, const float* __restrict__ bd,
               float* __restrict__ out) {
    __shared__ __half2 Wh2[FDIM * KP2];
    __shared__ __half2 Uh2[UNITS * KP2];
    __shared__ float   xs[FDIM * BP];
    __shared__ float   hs[UNITS * BP];
    __shared__ float   sX[KP * BP];
    __shared__ float   sU[KP * BP];

    const int tid = threadIdx.x;
    const int bl  = tid & 7;        // batch lane 0..7
    const int kl  = tid >> 3;       // k group 0..39
    const int k0  = kl * 4;         // first of 4 gate columns
    const int b0  = blockIdx.x * NB;

    // ---- load weights into LDS as f16 (zero-pad cols >= 150) ----
    for (int idx = tid; idx < FDIM * KP2; idx += NTHREADS) {
        int f = idx / KP2, k2 = idx - f * KP2;
        int k = 2 * k2;
        float a = (k     < K3) ? W[f * K3 + k]     : 0.f;
        float c = (k + 1 < K3) ? W[f * K3 + k + 1] : 0.f;
        Wh2[idx] = __floats2half2_rn(a, c);
    }
    for (int idx = tid; idx < UNITS * KP2; idx += NTHREADS) {
        int i = idx / KP2, k2 = idx - i * KP2;
        int k = 2 * k2;
        float a = (k     < K3) ? U[i * K3 + k]     : 0.f;
        float c = (k + 1 < K3) ? U[i * K3 + k + 1] : 0.f;
        Uh2[idx] = __floats2half2_rn(a, c);
    }
    // h0 = 0
    for (int idx = tid; idx < UNITS * BP; idx += NTHREADS) hs[idx] = 0.f;

    // biases for this thread's 4 columns (0 for padded cols)
    float b0r[4], b1r[4];
    #pragma unroll
    for (int j = 0; j < 4; ++j) {
        int k = k0 + j;
        b0r[j] = (k < K3) ? bias[k]      : 0.f;
        b1r[j] = (k < K3) ? bias[K3 + k] : 0.f;
    }

    // ---- prologue: prefetch x tile for t=0 into registers ----
    // tile = NB*FDIM = 512 floats; thread covers idx and idx+320
    float xr0 = 0.f, xr1 = 0.f;
    {
        int f0 = tid & 63, bb0 = tid >> 6;
        xr0 = x[((size_t)(b0 + bb0) * TSTEPS + 0) * FDIM + f0];
        int idx1 = tid + NTHREADS;
        if (idx1 < NB * FDIM) {
            int f1 = idx1 & 63, bb1 = idx1 >> 6;
            xr1 = x[((size_t)(b0 + bb1) * TSTEPS + 0) * FDIM + f1];
        }
    }
    __syncthreads();   // weights + h0 visible

    for (int t = 0; t < TSTEPS; ++t) {
        // ---- stage prefetched x into LDS (transposed [f][b]) ----
        {
            int f0 = tid & 63, bb0 = tid >> 6;
            xs[f0 * BP + bb0] = xr0;
            int idx1 = tid + NTHREADS;
            if (idx1 < NB * FDIM) {
                int f1 = idx1 & 63, bb1 = idx1 >> 6;
                xs[f1 * BP + bb1] = xr1;
            }
        }
        __syncthreads();

        // ---- prefetch next x tile (overlaps with dot phase) ----
        if (t + 1 < TSTEPS) {
            int f0 = tid & 63, bb0 = tid >> 6;
            xr0 = x[((size_t)(b0 + bb0) * TSTEPS + (t + 1)) * FDIM + f0];
            int idx1 = tid + NTHREADS;
            if (idx1 < NB * FDIM) {
                int f1 = idx1 & 63, bb1 = idx1 >> 6;
                xr1 = x[((size_t)(b0 + bb1) * TSTEPS + (t + 1)) * FDIM + f1];
            }
        }

        // ---- dot phase: xp = x@W + b0 ; hp = h@U + b1 (4 cols each) ----
        float aX[4] = {b0r[0], b0r[1], b0r[2], b0r[3]};
        float aH[4] = {b1r[0], b1r[1], b1r[2], b1r[3]};
        #pragma unroll
        for (int f = 0; f < FDIM; ++f) {
            float xv = xs[f * BP + bl];
            __half2 wA = Wh2[f * KP2 + 2 * kl];
            __half2 wB = Wh2[f * KP2 + 2 * kl + 1];
            float2 fa = __half22float2(wA);
            float2 fb = __half22float2(wB);
            aX[0] = fmaf(xv, fa.x, aX[0]);
            aX[1] = fmaf(xv, fa.y, aX[1]);
            aX[2] = fmaf(xv, fb.x, aX[2]);
            aX[3] = fmaf(xv, fb.y, aX[3]);
        }
        #pragma unroll
        for (int i = 0; i < UNITS; ++i) {
            float hv = hs[i * BP + bl];
            __half2 uA = Uh2[i * KP2 + 2 * kl];
            __half2 uB = Uh2[i * KP2 + 2 * kl + 1];
            float2 fa = __half22float2(uA);
            float2 fb = __half22float2(uB);
            aH[0] = fmaf(hv, fa.x, aH[0]);
            aH[1] = fmaf(hv, fa.y, aH[1]);
            aH[2] = fmaf(hv, fb.x, aH[2]);
            aH[3] = fmaf(hv, fb.y, aH[3]);
        }
        #pragma unroll
        for (int j = 0; j < 4; ++j) {
            sX[(k0 + j) * BP + bl] = aX[j];
            sU[(k0 + j) * BP + bl] = aH[j];
        }
        __syncthreads();

        // ---- gate phase: combine columns (u, 50+u, 100+u) per (b,u) ----
        for (int idx = tid; idx < NB * UNITS; idx += NTHREADS) {
            int b = idx / UNITS;
            int u = idx - b * UNITS;
            float az = sX[u * BP + b]              + sU[u * BP + b];
            float ar = sX[(UNITS + u) * BP + b]    + sU[(UNITS + u) * BP + b];
            float xh = sX[(2 * UNITS + u) * BP + b];
            float hh = sU[(2 * UNITS + u) * BP + b];
            float z = 1.f / (1.f + __expf(-az));
            float r = 1.f / (1.f + __expf(-ar));
            float hc = fmaf(r, hh, xh);
            hc = fmaxf(hc, 0.f);
            float hold = hs[u * BP + b];
            hs[u * BP + b] = z * hold + (1.f - z) * hc;
        }
        __syncthreads();
    }

    // ---- epilogue: out[b] = h_T @ Wd + bd ----
    if (tid < NB) {
        float acc = bd[0];
        #pragma unroll
        for (int u = 0; u < UNITS; ++u)
            acc = fmaf(hs[u * BP + tid], Wd[u], acc);
        out[b0 + tid] = acc;
    }
}

extern "C" void kernel_launch(void* const* d_in, const int* in_sizes, int n_in,
                              void* d_out, int out_size, void* d_ws, size_t ws_size,
                              hipStream_t stream) {
    const float* x    = (const float*)d_in[0];
    const float* W    = (const float*)d_in[1];
    const float* U    = (const float*)d_in[2];
    const float* bias = (const float*)d_in[3];
    const float* Wd   = (const float*)d_in[4];
    const float* bd   = (const float*)d_in[5];
    float* out = (float*)d_out;

    dim3 grid(BATCH / NB);        // 512 blocks
    dim3 block(NTHREADS);         // 320 threads
    gru_fused<<<grid, block, 0, stream>>>(x, W, U, bias, Wd, bd, out);
}

// Round 2
// 308.338 us; speedup vs baseline: 2.9000x; 2.9000x over previous
//
#include <hip/hip_runtime.h>
#include <math.h>

typedef _Float16 v8h __attribute__((ext_vector_type(8)));
typedef float v4f __attribute__((ext_vector_type(4)));

#define UNITS    50
#define K3       150
#define FDIM     64
#define TSTEPS   128
#define BATCH    4096
#define NBATCH   16      // batch rows per block (one MFMA M-tile)
#define NTHREADS 192     // 3 waves: wave g handles gate g (0=z, 1=r, 2=h)
#define HS16_STRIDE 72   // halves per h row (50 used, 64 needed for ktile3, pad->72 for banks)
#define HS32_STRIDE 52
#define SP_STRIDE   20   // m-stride (words) in pre-activation planes

// LDS: sPre 4*64*20*4 = 20480 B, hs16 16*72*2 = 2304 B, hs32 16*52*4 = 3328 B  => ~26 KB

__global__ __launch_bounds__(NTHREADS, 1)
void gru_mfma(const float* __restrict__ x, const float* __restrict__ W,
              const float* __restrict__ U, const float* __restrict__ bias,
              const float* __restrict__ Wd, const float* __restrict__ bd,
              float* __restrict__ out) {
    __shared__ float    sPre[4 * 64 * SP_STRIDE];   // planes: 0=z, 1=r, 2=h_x, 3=h_h
    __shared__ _Float16 hs16[NBATCH * HS16_STRIDE]; // h state, f16, [m][k] (slots 50..71 = 0)
    __shared__ float    hs32[NBATCH * HS32_STRIDE]; // h state, f32 exact

    const int tid  = threadIdx.x;
    const int g    = tid >> 6;        // wave id = gate id (wave-uniform)
    const int lane = tid & 63;
    const int n    = lane & 15;       // B col-in-tile; also A batch row m
    const int quad = lane >> 4;
    const int b0   = blockIdx.x * NBATCH;

    // ---- zero h state ----
    for (int i = tid; i < NBATCH * HS16_STRIDE; i += NTHREADS) hs16[i] = (_Float16)0.f;
    for (int i = tid; i < NBATCH * HS32_STRIDE; i += NTHREADS) hs32[i] = 0.f;

    // ---- B fragments: combined rows [W(0..63); U(64..113); 0(114..127)], cols g*50 + c ----
    // lane n = col-in-tile, element j of ktile kt <-> k = kt*32 + quad*8 + j.
    // (Any consistent lane->k bijection used for BOTH A and B yields the correct dot.)
    v8h B[4][4];  // [ktile][ntile], resident in VGPRs for the whole kernel
    #pragma unroll
    for (int kt = 0; kt < 4; ++kt) {
        #pragma unroll
        for (int nt = 0; nt < 4; ++nt) {
            const int c = nt * 16 + n;
            v8h f;
            #pragma unroll
            for (int j = 0; j < 8; ++j) {
                const int k = kt * 32 + quad * 8 + j;
                float v = 0.f;
                if (c < UNITS) {
                    const int gcol = g * UNITS + c;
                    if (k < FDIM)              v = W[k * K3 + gcol];
                    else if (k < FDIM + UNITS) v = U[(k - FDIM) * K3 + gcol];
                }
                f[j] = (_Float16)v;
            }
            B[kt][nt] = f;
        }
    }

    // ---- per-thread bias values (one per ntile; col = nt*16 + n) ----
    float bZR[4], bX[4], bH[4];
    #pragma unroll
    for (int nt = 0; nt < 4; ++nt) {
        const int c = nt * 16 + n;
        float vzr = 0.f, vx = 0.f, vh = 0.f;
        if (c < UNITS) {
            if (g < 2) vzr = bias[g * UNITS + c] + bias[K3 + g * UNITS + c];
            vx = bias[2 * UNITS + c];        // b[0] for h-gate cols
            vh = bias[K3 + 2 * UNITS + c];   // b[1] for h-gate cols
        }
        bZR[nt] = vzr; bX[nt] = vx; bH[nt] = vh;
    }

    // ---- prefetch x tile for t=0: lane covers batch row (b0+n), k = quad*8..+7 (+32) ----
    const float* xbase = x + ((size_t)(b0 + n) * TSTEPS) * FDIM + quad * 8;
    v4f px0 = *(const v4f*)(xbase + 0);
    v4f px1 = *(const v4f*)(xbase + 4);
    v4f px2 = *(const v4f*)(xbase + 32);
    v4f px3 = *(const v4f*)(xbase + 36);

    __syncthreads();

    for (int t = 0; t < TSTEPS; ++t) {
        // ---- build A fragments ----
        v8h A0, A1, A2, A3;
        #pragma unroll
        for (int j = 0; j < 4; ++j) {
            A0[j]     = (_Float16)px0[j];
            A0[j + 4] = (_Float16)px1[j];
            A1[j]     = (_Float16)px2[j];
            A1[j + 4] = (_Float16)px3[j];
        }
        A2 = *(const v8h*)(&hs16[n * HS16_STRIDE + quad * 8]);        // h cols 0..31
        A3 = *(const v8h*)(&hs16[n * HS16_STRIDE + 32 + quad * 8]);   // h cols 32..63 (>=50 are 0)

        // ---- prefetch next step's x (overlaps MFMA + gate phases) ----
        if (t + 1 < TSTEPS) {
            const float* xp = xbase + (size_t)(t + 1) * FDIM;
            px0 = *(const v4f*)(xp + 0);
            px1 = *(const v4f*)(xp + 4);
            px2 = *(const v4f*)(xp + 32);
            px3 = *(const v4f*)(xp + 36);
        }

        // ---- MFMA phase ----
        if (g < 2) {
            // z / r gates: fully fused [x|h] @ [W;U], one accumulator
            #pragma unroll
            for (int nt = 0; nt < 4; ++nt) {
                v4f acc = {bZR[nt], bZR[nt], bZR[nt], bZR[nt]};
                acc = __builtin_amdgcn_mfma_f32_16x16x32_f16(A0, B[0][nt], acc, 0, 0, 0);
                acc = __builtin_amdgcn_mfma_f32_16x16x32_f16(A1, B[1][nt], acc, 0, 0, 0);
                acc = __builtin_amdgcn_mfma_f32_16x16x32_f16(A2, B[2][nt], acc, 0, 0, 0);
                acc = __builtin_amdgcn_mfma_f32_16x16x32_f16(A3, B[3][nt], acc, 0, 0, 0);
                const int c = nt * 16 + n;
                *(v4f*)(&sPre[(g * 64 + c) * SP_STRIDE + quad * 4]) = acc;
            }
        } else {
            // h gate: keep x-part and h-part separate (r multiplies only hh)
            #pragma unroll
            for (int nt = 0; nt < 4; ++nt) {
                v4f ax = {bX[nt], bX[nt], bX[nt], bX[nt]};
                ax = __builtin_amdgcn_mfma_f32_16x16x32_f16(A0, B[0][nt], ax, 0, 0, 0);
                ax = __builtin_amdgcn_mfma_f32_16x16x32_f16(A1, B[1][nt], ax, 0, 0, 0);
                v4f ah = {bH[nt], bH[nt], bH[nt], bH[nt]};
                ah = __builtin_amdgcn_mfma_f32_16x16x32_f16(A2, B[2][nt], ah, 0, 0, 0);
                ah = __builtin_amdgcn_mfma_f32_16x16x32_f16(A3, B[3][nt], ah, 0, 0, 0);
                const int c = nt * 16 + n;
                *(v4f*)(&sPre[(2 * 64 + c) * SP_STRIDE + quad * 4]) = ax;
                *(v4f*)(&sPre[(3 * 64 + c) * SP_STRIDE + quad * 4]) = ah;
            }
        }
        __syncthreads();

        // ---- gate phase: 16*50 = 800 (m,u) pairs over 192 threads ----
        for (int idx = tid; idx < NBATCH * UNITS; idx += NTHREADS) {
            const int u = idx >> 4;
            const int m = idx & 15;
            const float zp = sPre[(0 * 64 + u) * SP_STRIDE + m];
            const float rp = sPre[(1 * 64 + u) * SP_STRIDE + m];
            const float hx = sPre[(2 * 64 + u) * SP_STRIDE + m];
            const float hh = sPre[(3 * 64 + u) * SP_STRIDE + m];
            const float z  = 1.f / (1.f + __expf(-zp));
            const float r  = 1.f / (1.f + __expf(-rp));
            const float hc = fmaxf(fmaf(r, hh, hx), 0.f);
            const float ho = hs32[m * HS32_STRIDE + u];
            const float hn = fmaf(z, ho - hc, hc);   // z*ho + (1-z)*hc
            hs32[m * HS32_STRIDE + u] = hn;
            hs16[m * HS16_STRIDE + u] = (_Float16)hn;
        }
        __syncthreads();
    }

    // ---- epilogue: out[b] = h_T @ Wd + bd ----
    if (tid < NBATCH) {
        float acc = bd[0];
        #pragma unroll
        for (int u = 0; u < UNITS; ++u)
            acc = fmaf(hs32[tid * HS32_STRIDE + u], Wd[u], acc);
        out[b0 + tid] = acc;
    }
}

extern "C" void kernel_launch(void* const* d_in, const int* in_sizes, int n_in,
                              void* d_out, int out_size, void* d_ws, size_t ws_size,
                              hipStream_t stream) {
    const float* x    = (const float*)d_in[0];
    const float* W    = (const float*)d_in[1];
    const float* U    = (const float*)d_in[2];
    const float* bias = (const float*)d_in[3];
    const float* Wd   = (const float*)d_in[4];
    const float* bd   = (const float*)d_in[5];
    float* out = (float*)d_out;

    dim3 grid(BATCH / NBATCH);   // 256 blocks -> 1 per CU
    dim3 block(NTHREADS);        // 3 waves
    gru_mfma<<<grid, block, 0, stream>>>(x, W, U, bias, Wd, bd, out);
}